// Round 1
// baseline (657.761 us; speedup 1.0000x reference)
//
#include <hip/hip_runtime.h>

typedef short bf16x8 __attribute__((ext_vector_type(8)));
typedef float f32x4 __attribute__((ext_vector_type(4)));

#define RH 2560   // R*H = 10*256

__device__ __forceinline__ unsigned short f2bf(float f) {
  unsigned u = __float_as_uint(f);
  u += 0x7fffu + ((u >> 16) & 1u);   // RNE
  return (unsigned short)(u >> 16);
}
__device__ __forceinline__ float bf2f(unsigned short s) {
  return __uint_as_float(((unsigned)s) << 16);
}

// ---------------- CSR build ----------------
__global__ void zero_int(int* __restrict__ p, int n) {
  int i = blockIdx.x * 256 + threadIdx.x;
  if (i < n) p[i] = 0;
}
__global__ void hist_kernel(const int* __restrict__ ei, int E, int* __restrict__ cnt) {
  int e = blockIdx.x * 256 + threadIdx.x;
  if (e < E) atomicAdd(&cnt[ei[e]], 1);
}
__global__ __launch_bounds__(1024) void scan_excl(const int* __restrict__ cnt,
                                                  int* __restrict__ offs, int n) {
  __shared__ int buf[1024];
  int t = threadIdx.x;
  int carry = 0;
  if (t == 0) offs[0] = 0;
  for (int c0 = 0; c0 < n; c0 += 1024) {
    int v = (c0 + t < n) ? cnt[c0 + t] : 0;
    buf[t] = v;
    __syncthreads();
    for (int off = 1; off < 1024; off <<= 1) {
      int add = (t >= off) ? buf[t - off] : 0;
      __syncthreads();
      buf[t] += add;
      __syncthreads();
    }
    if (c0 + t < n) offs[c0 + t + 1] = carry + buf[t];
    carry += buf[1023];
    __syncthreads();
  }
}
__global__ void copy_int(const int* __restrict__ a, int* __restrict__ b, int n) {
  int i = blockIdx.x * 256 + threadIdx.x;
  if (i < n) b[i] = a[i];
}
__global__ void scatter_kernel(const int* __restrict__ ei, int E,
                               int* __restrict__ cursor, int* __restrict__ eord) {
  int e = blockIdx.x * 256 + threadIdx.x;
  if (e < E) {
    int s = atomicAdd(&cursor[ei[e]], 1);
    eord[s] = e;
  }
}

// ---------------- weight packing ----------------
// w [10][256][256] f32 -> Wt [256][2560] bf16, Wt[o][r*256+d] = w[r][d][o]
__global__ void packW(const float* __restrict__ w, unsigned short* __restrict__ Wt) {
  int idx = blockIdx.x * 256 + threadIdx.x;
  if (idx >= 256 * RH) return;
  int o = idx / RH;
  int k = idx - o * RH;
  Wt[idx] = f2bf(w[(size_t)k * 256 + o]);
}
// lw [512][256] f32 -> Wt [256][512] bf16
__global__ void packLin(const float* __restrict__ lw, unsigned short* __restrict__ Wt) {
  int idx = blockIdx.x * 256 + threadIdx.x;
  if (idx >= 256 * 512) return;
  int o = idx >> 9;
  int k = idx & 511;
  Wt[idx] = f2bf(lw[(size_t)k * 256 + o]);
}
// x -> output section 1 (x copy), emotions[:, :256] f32, em16[:, :256] bf16
__global__ void copyX(const float* __restrict__ x, float* __restrict__ xcopy,
                      float* __restrict__ em, unsigned short* __restrict__ em16, int total) {
  int idx = blockIdx.x * 256 + threadIdx.x;
  if (idx >= total) return;
  int nrow = idx >> 8, h = idx & 255;
  float v = x[idx];
  xcopy[idx] = v;
  em[(size_t)nrow * 512 + h] = v;
  em16[(size_t)nrow * 512 + h] = f2bf(v);
}

// ---------------- per-node aggregation -> S [N][2560] bf16 ----------------
template<bool SRCBF>
__global__ __launch_bounds__(256) void agg_kernel(
    const void* __restrict__ srcv,
    const int* __restrict__ eord,
    const int* __restrict__ offs,
    const int* __restrict__ ej,
    const int* __restrict__ etype,
    const float* __restrict__ enorm,
    unsigned short* __restrict__ S)
{
  __shared__ float acc[RH];
  __shared__ int sj[128];
  __shared__ int st[128];
  __shared__ float sn[128];
  const int i = blockIdx.x;
  const int t = threadIdx.x;
#pragma unroll
  for (int c = t; c < RH; c += 256) acc[c] = 0.0f;
  const int eb = offs[i], ee = offs[i + 1];
  for (int p0 = eb; p0 < ee; p0 += 128) {
    int np = min(128, ee - p0);
    __syncthreads();
    if (t < np) {
      int e = eord[p0 + t];
      sj[t] = ej[e];
      st[t] = etype[e];
      sn[t] = enorm[e] * 2.0f;  // forward passes edge_norm * 2
    }
    __syncthreads();
    for (int q = 0; q < np; ++q) {
      int jn = sj[q];
      float nrm = sn[q];
      int b = st[q] * 256 + t;   // slot == t (mod 256): race-free per thread
      float xv;
      if (SRCBF) xv = bf2f(((const unsigned short*)srcv)[(size_t)jn * 256 + t]);
      else       xv = ((const float*)srcv)[(size_t)jn * 256 + t];
      acc[b] += nrm * xv;
    }
  }
  int cc = ee - eb;
  float scale = 1.0f / (float)(cc > 1 ? cc : 1);
  size_t base = (size_t)i * RH;
#pragma unroll
  for (int c = t; c < RH; c += 256) S[base + c] = f2bf(acc[c] * scale);
}

// ---------------- GEMM: C[M x 256] = A[M x K](bf16) @ Bt[256 x K]^T ----------------
// MODE 0: sigmoid -> bout (ld 256, bf16)            [layer 1 out]
// MODE 1: f32 -> fout (ld 512) AND bf16 -> bout (ld 512)   [layer 2 out -> emotions]
// MODE 2: relu(v + bias[col]) -> fout (ld 256, f32) [lin layer -> hidden]
template<int MODE>
__global__ __launch_bounds__(256) void gemm128(
    const unsigned short* __restrict__ A,
    const unsigned short* __restrict__ Bt,
    int M, int K,
    float* __restrict__ fout,
    unsigned short* __restrict__ bout,
    const float* __restrict__ bias)
{
  __shared__ unsigned short At[128][40];
  __shared__ unsigned short Bs[128][40];
  const int tid = threadIdx.x;
  const int tileM = blockIdx.x * 128;
  const int tileN = blockIdx.y * 128;
  const int lane = tid & 63;
  const int wid = tid >> 6;
  const int wr = wid >> 1, wc = wid & 1;
  const int l15 = lane & 15, lq = lane >> 4;
  f32x4 acc[4][4] = {};
  const int nk = K >> 5;
  for (int kt = 0; kt < nk; ++kt) {
    __syncthreads();
#pragma unroll
    for (int p = 0; p < 2; ++p) {
      int c = tid + p * 256;
      int row = c >> 2;
      int ko = (c & 3) * 8;
      int gr = tileM + row;
      uint4 va = make_uint4(0u, 0u, 0u, 0u);
      if (gr < M) va = *reinterpret_cast<const uint4*>(A + (size_t)gr * K + kt * 32 + ko);
      *reinterpret_cast<uint4*>(&At[row][ko]) = va;
      uint4 vb = *reinterpret_cast<const uint4*>(Bt + (size_t)(tileN + row) * K + kt * 32 + ko);
      *reinterpret_cast<uint4*>(&Bs[row][ko]) = vb;
    }
    __syncthreads();
    bf16x8 af[4], bfr[4];
#pragma unroll
    for (int m = 0; m < 4; ++m)
      af[m] = *reinterpret_cast<const bf16x8*>(&At[wr * 64 + m * 16 + l15][lq * 8]);
#pragma unroll
    for (int n = 0; n < 4; ++n)
      bfr[n] = *reinterpret_cast<const bf16x8*>(&Bs[wc * 64 + n * 16 + l15][lq * 8]);
#pragma unroll
    for (int m = 0; m < 4; ++m)
#pragma unroll
      for (int n = 0; n < 4; ++n)
        acc[m][n] = __builtin_amdgcn_mfma_f32_16x16x32_bf16(af[m], bfr[n], acc[m][n], 0, 0, 0);
  }
  const int r0 = tileM + wr * 64;
  const int c0 = tileN + wc * 64;
#pragma unroll
  for (int m = 0; m < 4; ++m) {
#pragma unroll
    for (int n = 0; n < 4; ++n) {
      int col = c0 + n * 16 + l15;
      int rowb = r0 + m * 16 + lq * 4;
#pragma unroll
      for (int q = 0; q < 4; ++q) {
        int row = rowb + q;
        if (row < M) {
          float v = acc[m][n][q];
          if (MODE == 0) {
            float s = 1.0f / (1.0f + __expf(-v));
            bout[(size_t)row * 256 + col] = f2bf(s);
          } else if (MODE == 1) {
            fout[(size_t)row * 512 + col] = v;
            bout[(size_t)row * 512 + col] = f2bf(v);
          } else {
            float s = v + bias[col];
            s = s > 0.0f ? s : 0.0f;
            fout[(size_t)row * 256 + col] = s;
          }
        }
      }
    }
  }
}

// ---------------- fc + log_softmax ----------------
__global__ __launch_bounds__(256) void fc_lsm(const float* __restrict__ hidden,
                                              const float* __restrict__ fcW,
                                              const float* __restrict__ fcb,
                                              float* __restrict__ outlp, int N) {
  __shared__ float hs[32 * 256];
  __shared__ float fw[256 * 7];
  __shared__ float lg[32][8];
  const int t = threadIdx.x;
  const int nb = blockIdx.x * 32;
  for (int c = t; c < 256 * 7; c += 256) fw[c] = fcW[c];
  for (int c = t; c < 32 * 256; c += 256) {
    int node = nb + (c >> 8);
    hs[c] = (node < N) ? hidden[(size_t)node * 256 + (c & 255)] : 0.0f;
  }
  __syncthreads();
  if (t < 224) {
    int ln = t / 7, c = t - ln * 7;
    float s = fcb[c];
    for (int h = 0; h < 256; ++h) s += hs[ln * 256 + h] * fw[h * 7 + c];
    lg[ln][c] = s;
  }
  __syncthreads();
  if (t < 32 && nb + t < N) {
    float m = lg[t][0];
    for (int c = 1; c < 7; ++c) m = fmaxf(m, lg[t][c]);
    float sum = 0.0f;
    for (int c = 0; c < 7; ++c) sum += __expf(lg[t][c] - m);
    float ls = __logf(sum);
    for (int c = 0; c < 7; ++c) outlp[(size_t)(nb + t) * 7 + c] = lg[t][c] - m - ls;
  }
}

extern "C" void kernel_launch(void* const* d_in, const int* in_sizes, int n_in,
                              void* d_out, int out_size, void* d_ws, size_t ws_size,
                              hipStream_t stream) {
  const float* x     = (const float*)d_in[1];
  const int*   ei    = (const int*)d_in[2];     // [2][E]: row0 = dst i, row1 = src j
  const float* enorm = (const float*)d_in[3];
  const int*   etype = (const int*)d_in[4];
  const float* w1    = (const float*)d_in[7];
  const float* w2    = (const float*)d_in[8];
  const float* linW  = (const float*)d_in[9];
  const float* linb  = (const float*)d_in[10];
  const float* fcW   = (const float*)d_in[11];
  const float* fcb   = (const float*)d_in[12];
  float* out = (float*)d_out;

  const int N = in_sizes[0];        // 20000
  const int E = in_sizes[3];        // 640000

  char* ws = (char*)d_ws;
  size_t off = 0;
  auto carve = [&](size_t bytes) -> void* {
    void* p = ws + off;
    off += (bytes + 255) & ~(size_t)255;
    return p;
  };
  unsigned short* S    = (unsigned short*)carve((size_t)N * RH * 2);
  unsigned short* W1t  = (unsigned short*)carve((size_t)256 * RH * 2);
  unsigned short* W2t  = (unsigned short*)carve((size_t)256 * RH * 2);
  unsigned short* LWt  = (unsigned short*)carve((size_t)256 * 512 * 2);
  unsigned short* out1 = (unsigned short*)carve((size_t)N * 256 * 2);
  unsigned short* em16 = (unsigned short*)carve((size_t)N * 512 * 2);
  float* hidden        = (float*)carve((size_t)N * 256 * 4);
  int* cnt             = (int*)carve((size_t)N * 4);
  int* offs            = (int*)carve((size_t)(N + 1) * 4);
  int* cursor          = (int*)carve((size_t)N * 4);
  int* eord            = (int*)carve((size_t)E * 4);

  const int* e_i = ei;       // destination (aggregate here)
  const int* e_j = ei + E;   // source (gather x here)

  // CSR by destination
  zero_int<<<(N + 255) / 256, 256, 0, stream>>>(cnt, N);
  hist_kernel<<<(E + 255) / 256, 256, 0, stream>>>(e_i, E, cnt);
  scan_excl<<<1, 1024, 0, stream>>>(cnt, offs, N);
  copy_int<<<(N + 255) / 256, 256, 0, stream>>>(offs, cursor, N);
  scatter_kernel<<<(E + 255) / 256, 256, 0, stream>>>(e_i, E, cursor, eord);

  // weight packing + x copies
  packW<<<(256 * RH + 255) / 256, 256, 0, stream>>>(w1, W1t);
  packW<<<(256 * RH + 255) / 256, 256, 0, stream>>>(w2, W2t);
  packLin<<<(256 * 512 + 255) / 256, 256, 0, stream>>>(linW, LWt);
  copyX<<<((N * 256) + 255) / 256, 256, 0, stream>>>(
      x, out + (size_t)N * 7, out + (size_t)N * 263, em16, N * 256);

  dim3 gemm_grid((N + 127) / 128, 2);

  // layer 1
  agg_kernel<false><<<N, 256, 0, stream>>>(x, eord, offs, e_j, etype, enorm, S);
  gemm128<0><<<gemm_grid, 256, 0, stream>>>(S, W1t, N, RH, nullptr, out1, nullptr);

  // layer 2 -> emotions[:, 256:512] (f32 into d_out) + bf16 copy into em16
  agg_kernel<true><<<N, 256, 0, stream>>>(out1, eord, offs, e_j, etype, enorm, S);
  gemm128<1><<<gemm_grid, 256, 0, stream>>>(S, W2t, N, RH,
      out + (size_t)N * 263 + 256, em16 + 256, nullptr);

  // hidden = relu(emotions @ lin_W + lin_b)
  gemm128<2><<<gemm_grid, 256, 0, stream>>>(em16, LWt, N, 512, hidden, nullptr, linb);

  // logits + log_softmax
  fc_lsm<<<(N + 31) / 32, 256, 0, stream>>>(hidden, fcW, fcb, out, N);
}

// Round 2
// 641.282 us; speedup vs baseline: 1.0257x; 1.0257x over previous
//
#include <hip/hip_runtime.h>

typedef short bf16x8 __attribute__((ext_vector_type(8)));
typedef float f32x4 __attribute__((ext_vector_type(4)));

#define RH 2560   // R*H = 10*256

__device__ __forceinline__ unsigned short f2bf(float f) {
  unsigned u = __float_as_uint(f);
  u += 0x7fffu + ((u >> 16) & 1u);   // RNE
  return (unsigned short)(u >> 16);
}
__device__ __forceinline__ float bf2f(unsigned short s) {
  return __uint_as_float(((unsigned)s) << 16);
}

// ---------------- CSR build ----------------
__global__ void zero_int(int* __restrict__ p, int n) {
  int i = blockIdx.x * 256 + threadIdx.x;
  if (i < n) p[i] = 0;
}
__global__ void hist_kernel(const int* __restrict__ ei, int E, int* __restrict__ cnt) {
  int e = blockIdx.x * 256 + threadIdx.x;
  if (e < E) atomicAdd(&cnt[ei[e]], 1);
}
// single-pass scan: 1024 threads, ~20 elements serial each, one LDS scan of 1024
__global__ __launch_bounds__(1024) void scan_excl(const int* __restrict__ cnt,
                                                  int* __restrict__ offs, int n) {
  __shared__ int ps[1024];
  const int t = threadIdx.x;
  const int PER = (n + 1023) >> 10;
  const int base = t * PER;
  int s = 0;
  for (int k = 0; k < PER; ++k) {
    int idx = base + k;
    if (idx < n) s += cnt[idx];
  }
  ps[t] = s;
  __syncthreads();
  for (int off = 1; off < 1024; off <<= 1) {
    int add = (t >= off) ? ps[t - off] : 0;
    __syncthreads();
    ps[t] += add;
    __syncthreads();
  }
  int run = t ? ps[t - 1] : 0;
  for (int k = 0; k < PER; ++k) {
    int idx = base + k;
    if (idx < n) { offs[idx] = run; run += cnt[idx]; }
  }
  if (t == 1023) offs[n] = run;
}
__global__ void copy_int(const int* __restrict__ a, int* __restrict__ b, int n) {
  int i = blockIdx.x * 256 + threadIdx.x;
  if (i < n) b[i] = a[i];
}
// sort edge payloads into CSR order: coalesced consumption in agg
__global__ void scatter_kernel(const int* __restrict__ ei, const int* __restrict__ ejj,
                               const int* __restrict__ ety, const float* __restrict__ enm,
                               int E, int* __restrict__ cursor,
                               int* __restrict__ js, int* __restrict__ ts,
                               float* __restrict__ ns) {
  int e = blockIdx.x * 256 + threadIdx.x;
  if (e < E) {
    int s = atomicAdd(&cursor[ei[e]], 1);
    js[s] = ejj[e];
    ts[s] = ety[e];
    ns[s] = enm[e] * 2.0f;   // forward passes edge_norm * 2
  }
}

// ---------------- weight packing ----------------
__global__ void packW(const float* __restrict__ w, unsigned short* __restrict__ Wt) {
  int idx = blockIdx.x * 256 + threadIdx.x;
  if (idx >= 256 * RH) return;
  int o = idx / RH;
  int k = idx - o * RH;
  Wt[idx] = f2bf(w[(size_t)k * 256 + o]);
}
__global__ void packLin(const float* __restrict__ lw, unsigned short* __restrict__ Wt) {
  int idx = blockIdx.x * 256 + threadIdx.x;
  if (idx >= 256 * 512) return;
  int o = idx >> 9;
  int k = idx & 511;
  Wt[idx] = f2bf(lw[(size_t)k * 256 + o]);
}
// x -> out section 1 (x copy), emotions[:, :256] f32, em16[:, :256] bf16, x16 contiguous bf16
__global__ void copyX(const float* __restrict__ x, float* __restrict__ xcopy,
                      float* __restrict__ em, unsigned short* __restrict__ em16,
                      unsigned short* __restrict__ x16, int total) {
  int idx = blockIdx.x * 256 + threadIdx.x;
  if (idx >= total) return;
  int nrow = idx >> 8, h = idx & 255;
  float v = x[idx];
  xcopy[idx] = v;
  em[(size_t)nrow * 512 + h] = v;
  em16[(size_t)nrow * 512 + h] = f2bf(v);
  x16[idx] = f2bf(v);
}

// ---------------- per-node aggregation -> S [N][2560] bf16 ----------------
// Register accumulators (10 relations x 2 cols per lane); no LDS RMW chain.
__global__ __launch_bounds__(256) void agg_kernel2(
    const unsigned short* __restrict__ src,   // [N][256] bf16 contiguous rows
    const int* __restrict__ offs,
    const int* __restrict__ js,
    const int* __restrict__ ts,
    const float* __restrict__ ns,
    unsigned short* __restrict__ S)
{
  __shared__ int sj[128];
  __shared__ int st[128];
  __shared__ float sn[128];
  __shared__ float accs[10][256];
  const int i = blockIdx.x;
  const int t = threadIdx.x;
  const int wave = t >> 6;
  const int lane = t & 63;
  const int pair = wave >> 1;             // edge-stream parity (0/1)
  const int wi = wave & 1;                // column half
  const int colbase = (wi * 64 + lane) * 2;
  float acc[10][2] = {};
  const int eb = offs[i], ee = offs[i + 1];
  for (int p0 = eb; p0 < ee; p0 += 128) {
    int np = min(128, ee - p0);
    __syncthreads();
    if (t < np) {
      sj[t] = js[p0 + t];
      st[t] = ts[p0 + t];
      sn[t] = ns[p0 + t];
    }
    __syncthreads();
    for (int q = pair; q < np; q += 2) {
      int jn = __builtin_amdgcn_readfirstlane(sj[q]);
      int tr = __builtin_amdgcn_readfirstlane(st[q]);
      float nr = __uint_as_float(__builtin_amdgcn_readfirstlane(__float_as_uint(sn[q])));
      unsigned v = *reinterpret_cast<const unsigned*>(src + (size_t)jn * 256 + colbase);
      float x0 = bf2f((unsigned short)(v & 0xffffu));
      float x1 = bf2f((unsigned short)(v >> 16));
#pragma unroll
      for (int r = 0; r < 10; ++r) {
        float wr = (tr == r) ? nr : 0.0f;   // uniform -> SALU select
        acc[r][0] += wr * x0;
        acc[r][1] += wr * x1;
      }
    }
  }
  // merge the two edge-stream partials via LDS
  if (pair == 0) {
#pragma unroll
    for (int r = 0; r < 10; ++r) {
      accs[r][colbase] = acc[r][0];
      accs[r][colbase + 1] = acc[r][1];
    }
  }
  __syncthreads();
  if (pair == 1) {
#pragma unroll
    for (int r = 0; r < 10; ++r) {
      accs[r][colbase] += acc[r][0];
      accs[r][colbase + 1] += acc[r][1];
    }
  }
  __syncthreads();
  int cc = ee - eb;
  float scale = 1.0f / (float)(cc > 1 ? cc : 1);
  size_t base = (size_t)i * RH;
#pragma unroll
  for (int it = 0; it < 5; ++it) {
    int c = it * 512 + t * 2;
    float a0 = accs[c >> 8][c & 255] * scale;
    float a1 = accs[c >> 8][(c & 255) + 1] * scale;
    unsigned pk = (unsigned)f2bf(a0) | ((unsigned)f2bf(a1) << 16);
    *reinterpret_cast<unsigned*>(S + base + c) = pk;
  }
}

// ---------------- GEMM: C[M x 256] = A[M x K](bf16) @ Bt[256 x K]^T ----------------
template<int MODE>
__global__ __launch_bounds__(256) void gemm128(
    const unsigned short* __restrict__ A,
    const unsigned short* __restrict__ Bt,
    int M, int K,
    float* __restrict__ fout,
    unsigned short* __restrict__ bout,
    const float* __restrict__ bias)
{
  __shared__ unsigned short At[128][40];
  __shared__ unsigned short Bs[128][40];
  const int tid = threadIdx.x;
  const int tileM = blockIdx.x * 128;
  const int tileN = blockIdx.y * 128;
  const int lane = tid & 63;
  const int wid = tid >> 6;
  const int wr = wid >> 1, wc = wid & 1;
  const int l15 = lane & 15, lq = lane >> 4;
  f32x4 acc[4][4] = {};
  const int nk = K >> 5;
  for (int kt = 0; kt < nk; ++kt) {
    __syncthreads();
#pragma unroll
    for (int p = 0; p < 2; ++p) {
      int c = tid + p * 256;
      int row = c >> 2;
      int ko = (c & 3) * 8;
      int gr = tileM + row;
      uint4 va = make_uint4(0u, 0u, 0u, 0u);
      if (gr < M) va = *reinterpret_cast<const uint4*>(A + (size_t)gr * K + kt * 32 + ko);
      *reinterpret_cast<uint4*>(&At[row][ko]) = va;
      uint4 vb = *reinterpret_cast<const uint4*>(Bt + (size_t)(tileN + row) * K + kt * 32 + ko);
      *reinterpret_cast<uint4*>(&Bs[row][ko]) = vb;
    }
    __syncthreads();
    bf16x8 af[4], bfr[4];
#pragma unroll
    for (int m = 0; m < 4; ++m)
      af[m] = *reinterpret_cast<const bf16x8*>(&At[wr * 64 + m * 16 + l15][lq * 8]);
#pragma unroll
    for (int n = 0; n < 4; ++n)
      bfr[n] = *reinterpret_cast<const bf16x8*>(&Bs[wc * 64 + n * 16 + l15][lq * 8]);
#pragma unroll
    for (int m = 0; m < 4; ++m)
#pragma unroll
      for (int n = 0; n < 4; ++n)
        acc[m][n] = __builtin_amdgcn_mfma_f32_16x16x32_bf16(af[m], bfr[n], acc[m][n], 0, 0, 0);
  }
  const int r0 = tileM + wr * 64;
  const int c0 = tileN + wc * 64;
#pragma unroll
  for (int m = 0; m < 4; ++m) {
#pragma unroll
    for (int n = 0; n < 4; ++n) {
      int col = c0 + n * 16 + l15;
      int rowb = r0 + m * 16 + lq * 4;
#pragma unroll
      for (int q = 0; q < 4; ++q) {
        int row = rowb + q;
        if (row < M) {
          float v = acc[m][n][q];
          if (MODE == 0) {
            float s = 1.0f / (1.0f + __expf(-v));
            bout[(size_t)row * 256 + col] = f2bf(s);
          } else if (MODE == 1) {
            fout[(size_t)row * 512 + col] = v;
            bout[(size_t)row * 512 + col] = f2bf(v);
          } else {
            float s = v + bias[col];
            s = s > 0.0f ? s : 0.0f;
            fout[(size_t)row * 256 + col] = s;
          }
        }
      }
    }
  }
}

// ---------------- fc + log_softmax ----------------
__global__ __launch_bounds__(256) void fc_lsm(const float* __restrict__ hidden,
                                              const float* __restrict__ fcW,
                                              const float* __restrict__ fcb,
                                              float* __restrict__ outlp, int N) {
  __shared__ float hs[32 * 256];
  __shared__ float fw[256 * 7];
  __shared__ float lg[32][8];
  const int t = threadIdx.x;
  const int nb = blockIdx.x * 32;
  for (int c = t; c < 256 * 7; c += 256) fw[c] = fcW[c];
  for (int c = t; c < 32 * 256; c += 256) {
    int node = nb + (c >> 8);
    hs[c] = (node < N) ? hidden[(size_t)node * 256 + (c & 255)] : 0.0f;
  }
  __syncthreads();
  if (t < 224) {
    int ln = t / 7, c = t - ln * 7;
    float s = fcb[c];
    for (int h = 0; h < 256; ++h) s += hs[ln * 256 + h] * fw[h * 7 + c];
    lg[ln][c] = s;
  }
  __syncthreads();
  if (t < 32 && nb + t < N) {
    float m = lg[t][0];
    for (int c = 1; c < 7; ++c) m = fmaxf(m, lg[t][c]);
    float sum = 0.0f;
    for (int c = 0; c < 7; ++c) sum += __expf(lg[t][c] - m);
    float ls = __logf(sum);
    for (int c = 0; c < 7; ++c) outlp[(size_t)(nb + t) * 7 + c] = lg[t][c] - m - ls;
  }
}

extern "C" void kernel_launch(void* const* d_in, const int* in_sizes, int n_in,
                              void* d_out, int out_size, void* d_ws, size_t ws_size,
                              hipStream_t stream) {
  const float* x     = (const float*)d_in[1];
  const int*   ei    = (const int*)d_in[2];     // [2][E]: row0 = dst i, row1 = src j
  const float* enorm = (const float*)d_in[3];
  const int*   etype = (const int*)d_in[4];
  const float* w1    = (const float*)d_in[7];
  const float* w2    = (const float*)d_in[8];
  const float* linW  = (const float*)d_in[9];
  const float* linb  = (const float*)d_in[10];
  const float* fcW   = (const float*)d_in[11];
  const float* fcb   = (const float*)d_in[12];
  float* out = (float*)d_out;

  const int N = in_sizes[0];        // 20000
  const int E = in_sizes[3];        // 640000

  char* ws = (char*)d_ws;
  size_t off = 0;
  auto carve = [&](size_t bytes) -> void* {
    void* p = ws + off;
    off += (bytes + 255) & ~(size_t)255;
    return p;
  };
  unsigned short* S    = (unsigned short*)carve((size_t)N * RH * 2);
  unsigned short* W1t  = (unsigned short*)carve((size_t)256 * RH * 2);
  unsigned short* W2t  = (unsigned short*)carve((size_t)256 * RH * 2);
  unsigned short* LWt  = (unsigned short*)carve((size_t)256 * 512 * 2);
  unsigned short* out1 = (unsigned short*)carve((size_t)N * 256 * 2);
  unsigned short* em16 = (unsigned short*)carve((size_t)N * 512 * 2);
  unsigned short* x16  = (unsigned short*)carve((size_t)N * 256 * 2);
  int* cnt             = (int*)carve((size_t)N * 4);
  int* offs            = (int*)carve((size_t)(N + 1) * 4);
  int* cursor          = (int*)carve((size_t)N * 4);
  int* js              = (int*)carve((size_t)E * 4);
  int* ts              = (int*)carve((size_t)E * 4);
  float* ns            = (float*)carve((size_t)E * 4);
  float* hidden        = (float*)S;   // alias: S dead after gemm2, hidden born at gemm3

  const int* e_i = ei;       // destination (aggregate here)
  const int* e_j = ei + E;   // source (gather x here)

  // CSR by destination + payload sort
  zero_int<<<(N + 255) / 256, 256, 0, stream>>>(cnt, N);
  hist_kernel<<<(E + 255) / 256, 256, 0, stream>>>(e_i, E, cnt);
  scan_excl<<<1, 1024, 0, stream>>>(cnt, offs, N);
  copy_int<<<(N + 255) / 256, 256, 0, stream>>>(offs, cursor, N);
  scatter_kernel<<<(E + 255) / 256, 256, 0, stream>>>(e_i, e_j, etype, enorm, E,
                                                      cursor, js, ts, ns);

  // weight packing + x copies
  packW<<<(256 * RH + 255) / 256, 256, 0, stream>>>(w1, W1t);
  packW<<<(256 * RH + 255) / 256, 256, 0, stream>>>(w2, W2t);
  packLin<<<(256 * 512 + 255) / 256, 256, 0, stream>>>(linW, LWt);
  copyX<<<((N * 256) + 255) / 256, 256, 0, stream>>>(
      x, out + (size_t)N * 7, out + (size_t)N * 263, em16, x16, N * 256);

  dim3 gemm_grid((N + 127) / 128, 2);

  // layer 1
  agg_kernel2<<<N, 256, 0, stream>>>(x16, offs, js, ts, ns, S);
  gemm128<0><<<gemm_grid, 256, 0, stream>>>(S, W1t, N, RH, nullptr, out1, nullptr);

  // layer 2 -> emotions[:, 256:512] (f32 into d_out) + bf16 copy into em16
  agg_kernel2<<<N, 256, 0, stream>>>(out1, offs, js, ts, ns, S);
  gemm128<1><<<gemm_grid, 256, 0, stream>>>(S, W2t, N, RH,
      out + (size_t)N * 263 + 256, em16 + 256, nullptr);

  // hidden = relu(emotions @ lin_W + lin_b)
  gemm128<2><<<gemm_grid, 256, 0, stream>>>(em16, LWt, N, 512, hidden, nullptr, linb);

  // logits + log_softmax
  fc_lsm<<<(N + 31) / 32, 256, 0, stream>>>(hidden, fcW, fcb, out, N);
}